// Round 12
// baseline (383.910 us; speedup 1.0000x reference)
//
#include <hip/hip_runtime.h>

typedef unsigned short u16;
typedef unsigned int   u32;
typedef __attribute__((ext_vector_type(4))) float f32x4;

#define N_NODES    100000
#define N_EDGES    1600000
#define HID        64
#define NUM_GRAPHS 128
#define BN_EPS     1e-5f

#define BSH        9                     // 512 nodes per bucket
#define NB         196                   // ceil(100000/512)
#define SC_T       2048                  // edges per scatter block
#define SC_NB      782                   // ceil(1600000/2048)
#define MAXBE      12288                 // LDS cap for edges/bucket

#define NT_MLP     1563                  // ceil(100000/64) 64-node tiles
#define MLP_BLKS   782                   // 2 waves/block -> 1564 waves
#define NPARTS     1564
#define WS         68                    // padded LDS row stride (f32 / u32 elems)

#define RED_BLKS   64                    // BN reduction blocks (fused last-block finalize)
#define RED_CHUNK  25                    // ceil(NPARTS / RED_BLKS)

#define POOL_BLKS  391                   // ceil(100000/256)

__device__ __forceinline__ float bf2f(u16 u) { return __uint_as_float(((u32)u) << 16); }
__device__ __forceinline__ u16 f2bf(float f) {           // RNE
  u32 u = __float_as_uint(f);
  u32 r = ((u >> 16) & 1u) + 0x7FFFu;
  return (u16)((u + r) >> 16);
}
__device__ __forceinline__ u32 cvtpk(float lo, float hi) {  // pack 2 f32 -> 2 bf16
  u32 r;
  asm("v_cvt_pk_bf16_f32 %0, %1, %2" : "=v"(r) : "v"(lo), "v"(hi));
  return r;
}

// ================= CSR build v3: LDS counting-sort, streaming writes =================

__global__ void k_hist(const int* __restrict__ dst, int* __restrict__ blockHist) {
  __shared__ int h[NB];
  for (int i = threadIdx.x; i < NB; i += 256) h[i] = 0;
  __syncthreads();
  int base = blockIdx.x * SC_T;
  int cnt = min(SC_T, N_EDGES - base);
  for (int i = threadIdx.x; i < cnt; i += 256) atomicAdd(&h[dst[base + i] >> BSH], 1);
  __syncthreads();
  for (int i = threadIdx.x; i < NB; i += 256) blockHist[blockIdx.x * NB + i] = h[i];
}

__global__ void k_hscan(const int* __restrict__ blockHist, int* __restrict__ blockBase,
                        int* __restrict__ bucketTot) {
  __shared__ int s[1024];
  int b = blockIdx.x, t = threadIdx.x;
  int v = (t < SC_NB) ? blockHist[t * NB + b] : 0;
  s[t] = v;
  __syncthreads();
  for (int d = 1; d < 1024; d <<= 1) {
    int x = (t >= d) ? s[t - d] : 0; __syncthreads();
    s[t] += x; __syncthreads();
  }
  if (t < SC_NB) blockBase[t * NB + b] = s[t] - v;
  if (t == 1023) bucketTot[b] = s[1023];
}

__global__ void k_bscan(const int* __restrict__ bucketTot, int* __restrict__ bucketStart) {
  __shared__ int s[256];
  int t = threadIdx.x;
  int v = (t < NB) ? bucketTot[t] : 0;
  s[t] = v;
  __syncthreads();
  for (int d = 1; d < 256; d <<= 1) {
    int x = (t >= d) ? s[t - d] : 0; __syncthreads();
    s[t] += x; __syncthreads();
  }
  if (t < NB) bucketStart[t] = s[t] - v;
  if (t == NB - 1) bucketStart[NB] = s[t];
}

__global__ __launch_bounds__(256) void k_scatter(
    const int* __restrict__ src, const int* __restrict__ dst,
    const int* __restrict__ blockBase, const int* __restrict__ bucketStart,
    int2* __restrict__ bout) {
  __shared__ int2 stage[SC_T];
  __shared__ int2 sorted[SC_T];
  __shared__ int lhist[NB], lscan[NB], lcur[NB];
  __shared__ int sbuf[256];
  int base = blockIdx.x * SC_T;
  int cnt = min(SC_T, N_EDGES - base);
  for (int i = threadIdx.x; i < NB; i += 256) lhist[i] = 0;
  __syncthreads();
  for (int i = threadIdx.x; i < cnt; i += 256) {
    int d = dst[base + i];
    stage[i] = make_int2(src[base + i], d);
    atomicAdd(&lhist[d >> BSH], 1);
  }
  __syncthreads();
  int t = threadIdx.x;
  int v = (t < NB) ? lhist[t] : 0;
  sbuf[t] = v;
  __syncthreads();
  for (int d = 1; d < 256; d <<= 1) {
    int x = (t >= d) ? sbuf[t - d] : 0; __syncthreads();
    sbuf[t] += x; __syncthreads();
  }
  if (t < NB) { lscan[t] = sbuf[t] - v; lcur[t] = sbuf[t] - v; }
  __syncthreads();
  for (int i = threadIdx.x; i < cnt; i += 256) {
    int2 e = stage[i];
    int pos = atomicAdd(&lcur[e.y >> BSH], 1);
    sorted[pos] = e;
  }
  __syncthreads();
  int bb = blockIdx.x * NB;
  for (int i = threadIdx.x; i < cnt; i += 256) {
    int2 e = sorted[i];
    int bk = e.y >> BSH;
    bout[bucketStart[bk] + blockBase[bb + bk] + (i - lscan[bk])] = e;
  }
}

__global__ __launch_bounds__(512) void k_build(
    const int2* __restrict__ bout, const int* __restrict__ bucketStart,
    int* __restrict__ off, int* __restrict__ esrc) {
  __shared__ int lcnt[512], ls[512], lcur[512];
  __shared__ int lout[MAXBE];
  int b = blockIdx.x;
  int node0 = b << BSH;
  int ncnt = min(512, N_NODES - node0);
  int e0 = bucketStart[b], e1 = bucketStart[b + 1];
  int t = threadIdx.x;
  lcnt[t] = 0;
  __syncthreads();
  for (int i = e0 + t; i < e1; i += 512) atomicAdd(&lcnt[bout[i].y - node0], 1);
  __syncthreads();
  int v = lcnt[t];
  ls[t] = v;
  __syncthreads();
  for (int d = 1; d < 512; d <<= 1) {
    int x = (t >= d) ? ls[t - d] : 0; __syncthreads();
    ls[t] += x; __syncthreads();
  }
  int excl = ls[t] - v;
  if (t < ncnt) off[node0 + t] = e0 + excl;
  if (b == NB - 1 && t == 0) off[N_NODES] = e1;
  lcur[t] = excl;
  __syncthreads();
  for (int i = e0 + t; i < e1; i += 512) {
    int2 e = bout[i];
    int pos = atomicAdd(&lcur[e.y - node0], 1);
    lout[pos] = e.x;
  }
  __syncthreads();
  int n = e1 - e0;
  for (int i = t; i < n; i += 512) esrc[e0 + i] = lout[i];
}

// ================= misc =================

__global__ void k_tobf16(const float* __restrict__ in, u16* __restrict__ out) {
  int i = blockIdx.x * blockDim.x + threadIdx.x;
  float4 v = ((const float4*)in)[i];
  ushort4 o;
  o.x = f2bf(v.x); o.y = f2bf(v.y); o.z = f2bf(v.z); o.w = f2bf(v.w);
  ((ushort4*)out)[i] = o;
}

// ================= per-layer kernels =================

template<bool BN>
__global__ void k_gather(const u16* __restrict__ Xb, const int* __restrict__ off,
                         const int* __restrict__ esrc, const float* __restrict__ sc,
                         u16* __restrict__ aggB) {
  int gid = blockIdx.x * blockDim.x + threadIdx.x;
  int w = gid >> 6;
  int t = gid & 63;
  if (w >= N_NODES) return;
  float scale = 1.f, shift = 0.f;
  if (BN) { scale = sc[t]; shift = sc[64 + t]; }
  int s0 = off[w], s1 = off[w + 1];
  float self = bf2f(Xb[((u32)w << 6) + t]);
  float acc = BN ? fmaxf(fmaf(self, scale, shift), 0.f) : self;
  int i = s0;
  // 16-wide: covers the average degree (16) in one latency round
  for (; i + 16 <= s1; i += 16) {
    float v[16];
#pragma unroll
    for (int j = 0; j < 16; ++j)
      v[j] = bf2f(Xb[((u32)esrc[i + j] << 6) + t]);
    if (BN) {
#pragma unroll
      for (int j = 0; j < 16; ++j)
        v[j] = fmaxf(fmaf(v[j], scale, shift), 0.f);
    }
    float s01 = (v[0] + v[1]) + (v[2] + v[3]);
    float s23 = (v[4] + v[5]) + (v[6] + v[7]);
    float s45 = (v[8] + v[9]) + (v[10] + v[11]);
    float s67 = (v[12] + v[13]) + (v[14] + v[15]);
    acc += (s01 + s23) + (s45 + s67);
  }
  for (; i + 4 <= s1; i += 4) {
    float v0 = bf2f(Xb[((u32)esrc[i + 0] << 6) + t]);
    float v1 = bf2f(Xb[((u32)esrc[i + 1] << 6) + t]);
    float v2 = bf2f(Xb[((u32)esrc[i + 2] << 6) + t]);
    float v3 = bf2f(Xb[((u32)esrc[i + 3] << 6) + t]);
    if (BN) {
      v0 = fmaxf(fmaf(v0, scale, shift), 0.f);
      v1 = fmaxf(fmaf(v1, scale, shift), 0.f);
      v2 = fmaxf(fmaf(v2, scale, shift), 0.f);
      v3 = fmaxf(fmaf(v3, scale, shift), 0.f);
    }
    acc += (v0 + v1) + (v2 + v3);
  }
  for (; i < s1; ++i) {
    float v = bf2f(Xb[((u32)esrc[i] << 6) + t]);
    if (BN) v = fmaxf(fmaf(v, scale, shift), 0.f);
    acc += v;
  }
  aggB[((u32)w << 6) + t] = f2bf(acc);
}

// Register-tiled vector GEMM MLP v4: wave = 64-node tile, lane = 8x8 D sub-block.
__global__ __launch_bounds__(128) void k_mlp(
    const u16* __restrict__ AGGB,
    const float* __restrict__ w1, const float* __restrict__ b1,
    const float* __restrict__ w2, const float* __restrict__ b2,
    u16* __restrict__ OUTB, float* __restrict__ part) {
  __shared__ float Wl[2][64 * WS];       // W1, W2 fp32, padded rows
  __shared__ u32 Abuf[2][32 * WS];       // per-wave A/H tile: [kp][m] bf16-pairs
  int wv = threadIdx.x >> 6, lane = threadIdx.x & 63;

  for (int i = threadIdx.x; i < 4096; i += 128) {
    int r = i >> 6, c = i & 63;
    Wl[0][r * WS + c] = w1[i];
    Wl[1][r * WS + c] = w2[i];
  }
  __syncthreads();

  int gw = blockIdx.x * 2 + wv;
  int mg = lane >> 3, ng = lane & 7;
  int m0 = mg * 8, n0 = ng * 8;

  if (gw >= NT_MLP) {                    // idle tail wave: zero its stats slot
    if (gw < NPARTS)
      for (int i = lane; i < 128; i += 64) part[gw * 128 + i] = 0.f;
    return;
  }

  u32* A2 = Abuf[wv];
  int nodeBase = gw * 64;
  const u32* srcp = (const u32*)(AGGB + (size_t)nodeBase * 64);
  bool full = (nodeBase + 64 <= N_NODES);
  if (full) {
#pragma unroll
    for (int i = 0; i < 32; ++i) {
      int idx = lane + i * 64;           // idx = m*32 + kp
      A2[(idx & 31) * WS + (idx >> 5)] = srcp[idx];
    }
  } else {
    for (int i = 0; i < 32; ++i) {
      int idx = lane + i * 64;
      int m = idx >> 5;
      A2[(idx & 31) * WS + m] = (nodeBase + m < N_NODES) ? srcp[idx] : 0u;
    }
  }

  float acc[8][8];
#pragma unroll
  for (int c = 0; c < 8; ++c) {
    float bv = b1[n0 + c];
#pragma unroll
    for (int r = 0; r < 8; ++r) acc[r][c] = bv;
  }

  // ---- GEMM1 ----
  {
    const float* W = Wl[0];
#pragma unroll 4
    for (int kp = 0; kp < 32; ++kp) {
      uint4 amA = *(const uint4*)(A2 + kp * WS + m0);
      uint4 amB = *(const uint4*)(A2 + kp * WS + m0 + 4);
      f32x4 w0a = *(const f32x4*)(W + (2 * kp) * WS + n0);
      f32x4 w0b = *(const f32x4*)(W + (2 * kp) * WS + n0 + 4);
      f32x4 w1a = *(const f32x4*)(W + (2 * kp + 1) * WS + n0);
      f32x4 w1b = *(const f32x4*)(W + (2 * kp + 1) * WS + n0 + 4);
      float wlo[8], whi[8];
#pragma unroll
      for (int c = 0; c < 4; ++c) {
        wlo[c] = w0a[c]; wlo[c + 4] = w0b[c];
        whi[c] = w1a[c]; whi[c + 4] = w1b[c];
      }
      u32 av[8] = {amA.x, amA.y, amA.z, amA.w, amB.x, amB.y, amB.z, amB.w};
#pragma unroll
      for (int r = 0; r < 8; ++r) {
        float alo = __uint_as_float(av[r] << 16);
        float ahi = __uint_as_float(av[r] & 0xffff0000u);
#pragma unroll
        for (int c = 0; c < 8; ++c) {
          acc[r][c] = fmaf(alo, wlo[c], acc[r][c]);
          acc[r][c] = fmaf(ahi, whi[c], acc[r][c]);
        }
      }
    }
  }

  // relu -> pack bf16 -> H tile in-place (WAR on A2: drain LDS queue first)
  asm volatile("s_waitcnt lgkmcnt(0)" ::: "memory");
#pragma unroll
  for (int p = 0; p < 4; ++p) {
    u32 pk[8];
#pragma unroll
    for (int r = 0; r < 8; ++r)
      pk[r] = cvtpk(fmaxf(acc[r][2 * p], 0.f), fmaxf(acc[r][2 * p + 1], 0.f));
    int kp = ng * 4 + p;
    *(uint4*)(A2 + kp * WS + m0)     = make_uint4(pk[0], pk[1], pk[2], pk[3]);
    *(uint4*)(A2 + kp * WS + m0 + 4) = make_uint4(pk[4], pk[5], pk[6], pk[7]);
  }
  asm volatile("s_waitcnt lgkmcnt(0)" ::: "memory");

#pragma unroll
  for (int c = 0; c < 8; ++c) {
    float bv = b2[n0 + c];
#pragma unroll
    for (int r = 0; r < 8; ++r) acc[r][c] = bv;
  }

  // ---- GEMM2 ----
  {
    const float* W = Wl[1];
#pragma unroll 4
    for (int kp = 0; kp < 32; ++kp) {
      uint4 amA = *(const uint4*)(A2 + kp * WS + m0);
      uint4 amB = *(const uint4*)(A2 + kp * WS + m0 + 4);
      f32x4 w0a = *(const f32x4*)(W + (2 * kp) * WS + n0);
      f32x4 w0b = *(const f32x4*)(W + (2 * kp) * WS + n0 + 4);
      f32x4 w1a = *(const f32x4*)(W + (2 * kp + 1) * WS + n0);
      f32x4 w1b = *(const f32x4*)(W + (2 * kp + 1) * WS + n0 + 4);
      float wlo[8], whi[8];
#pragma unroll
      for (int c = 0; c < 4; ++c) {
        wlo[c] = w0a[c]; wlo[c + 4] = w0b[c];
        whi[c] = w1a[c]; whi[c + 4] = w1b[c];
      }
      u32 av[8] = {amA.x, amA.y, amA.z, amA.w, amB.x, amB.y, amB.z, amB.w};
#pragma unroll
      for (int r = 0; r < 8; ++r) {
        float alo = __uint_as_float(av[r] << 16);
        float ahi = __uint_as_float(av[r] & 0xffff0000u);
#pragma unroll
        for (int c = 0; c < 8; ++c) {
          acc[r][c] = fmaf(alo, wlo[c], acc[r][c]);
          acc[r][c] = fmaf(ahi, whi[c], acc[r][c]);
        }
      }
    }
  }

  // ---- epilogue: bf16 store + fused BN stats (fp32, valid rows only) ----
  float sstat[8], qstat[8];
#pragma unroll
  for (int c = 0; c < 8; ++c) { sstat[c] = 0.f; qstat[c] = 0.f; }
#pragma unroll
  for (int r = 0; r < 8; ++r) {
    int gm = nodeBase + m0 + r;
    if (gm < N_NODES) {
      uint4 o;
      o.x = cvtpk(acc[r][0], acc[r][1]);
      o.y = cvtpk(acc[r][2], acc[r][3]);
      o.z = cvtpk(acc[r][4], acc[r][5]);
      o.w = cvtpk(acc[r][6], acc[r][7]);
      *(uint4*)(OUTB + (size_t)gm * 64 + n0) = o;
#pragma unroll
      for (int c = 0; c < 8; ++c) {
        float v = acc[r][c];
        sstat[c] += v; qstat[c] += v * v;
      }
    }
  }
#pragma unroll
  for (int o = 8; o < 64; o <<= 1) {
#pragma unroll
    for (int c = 0; c < 8; ++c) {
      sstat[c] += __shfl_xor(sstat[c], o);
      qstat[c] += __shfl_xor(qstat[c], o);
    }
  }
  if (mg == 0) {
#pragma unroll
    for (int c = 0; c < 8; ++c) {
      part[gw * 128 + n0 + c] = sstat[c];
      part[gw * 128 + 64 + n0 + c] = qstat[c];
    }
  }
}

// Fused BN reduction: stage-1 per-block partial + last-block finalize (rocPRIM pattern).
// counter must be zeroed before launch.
__global__ void k_bnfused(const float* __restrict__ part, float* __restrict__ part2,
                          int* counter, const float* __restrict__ gamma,
                          const float* __restrict__ beta, float* __restrict__ sc) {
  __shared__ float ls[256];
  __shared__ int amLast;
  int col = threadIdx.x & 127, sub = threadIdx.x >> 7;     // 256 threads
  int start = blockIdx.x * RED_CHUNK;
  int end = min(start + RED_CHUNK, NPARTS);
  float acc = 0.f;
  for (int r = start + sub; r < end; r += 2) acc += part[r * 128 + col];
  ls[threadIdx.x] = acc;
  __syncthreads();
  if (threadIdx.x < 128)
    part2[blockIdx.x * 128 + threadIdx.x] = ls[threadIdx.x] + ls[128 + threadIdx.x];
  __threadfence();                       // release: make part2 visible device-wide
  if (threadIdx.x == 0) amLast = (atomicAdd(counter, 1) == RED_BLKS - 1);
  __syncthreads();
  if (!amLast) return;
  __threadfence();                       // acquire: observe other blocks' part2
  float tot = 0.f;
  if (threadIdx.x < 128) {
    for (int b = 0; b < RED_BLKS; ++b) tot += part2[b * 128 + threadIdx.x];
    ls[threadIdx.x] = tot;
  }
  __syncthreads();
  if (threadIdx.x < 64) {
    float mean = ls[threadIdx.x] * (1.0f / N_NODES);
    float var  = ls[64 + threadIdx.x] * (1.0f / N_NODES) - mean * mean;
    float scale = gamma[threadIdx.x] * rsqrtf(var + BN_EPS);
    sc[threadIdx.x] = scale;
    sc[64 + threadIdx.x] = beta[threadIdx.x] - mean * scale;
  }
}

// ================= pooling + head (batch sorted -> segments) =================

__global__ void k_bounds(const int* __restrict__ batch, int* __restrict__ gstart) {
  int g = threadIdx.x;
  if (g > NUM_GRAPHS) return;
  int lo = 0, hi = N_NODES;
  while (lo < hi) {
    int mid = (lo + hi) >> 1;
    if (batch[mid] < g) lo = mid + 1; else hi = mid;
  }
  gstart[g] = lo;
}

__global__ void k_pool3(const u16* __restrict__ H, const int* __restrict__ batch,
                        const float* __restrict__ sc, float* __restrict__ psum) {
  int wv = threadIdx.x >> 6, lane = threadIdx.x & 63;
  int n0 = (blockIdx.x * 4 + wv) * 64;
  if (n0 >= N_NODES) return;
  int n1 = min(n0 + 64, N_NODES);
  float scale = sc[lane], shift = sc[64 + lane];
  int curg = batch[n0];
  float acc = 0.f;
  if (curg == batch[n1 - 1]) {
    int n = n0;
    for (; n + 8 <= n1; n += 8) {
      float v0 = fmaxf(fmaf(bf2f(H[(size_t)(n + 0) * HID + lane]), scale, shift), 0.f);
      float v1 = fmaxf(fmaf(bf2f(H[(size_t)(n + 1) * HID + lane]), scale, shift), 0.f);
      float v2 = fmaxf(fmaf(bf2f(H[(size_t)(n + 2) * HID + lane]), scale, shift), 0.f);
      float v3 = fmaxf(fmaf(bf2f(H[(size_t)(n + 3) * HID + lane]), scale, shift), 0.f);
      float v4 = fmaxf(fmaf(bf2f(H[(size_t)(n + 4) * HID + lane]), scale, shift), 0.f);
      float v5 = fmaxf(fmaf(bf2f(H[(size_t)(n + 5) * HID + lane]), scale, shift), 0.f);
      float v6 = fmaxf(fmaf(bf2f(H[(size_t)(n + 6) * HID + lane]), scale, shift), 0.f);
      float v7 = fmaxf(fmaf(bf2f(H[(size_t)(n + 7) * HID + lane]), scale, shift), 0.f);
      acc += ((v0 + v1) + (v2 + v3)) + ((v4 + v5) + (v6 + v7));
    }
    for (; n < n1; ++n)
      acc += fmaxf(fmaf(bf2f(H[(size_t)n * HID + lane]), scale, shift), 0.f);
    atomicAdd(&psum[curg * HID + lane], acc);
  } else {
    for (int n = n0; n < n1; ++n) {
      int g = batch[n];
      if (g != curg) { atomicAdd(&psum[curg * HID + lane], acc); acc = 0.f; curg = g; }
      acc += fmaxf(fmaf(bf2f(H[(size_t)n * HID + lane]), scale, shift), 0.f);
    }
    atomicAdd(&psum[curg * HID + lane], acc);
  }
}

__global__ void k_final(const float* __restrict__ psum, const int* __restrict__ gstart,
                        const float* __restrict__ fw1, const float* __restrict__ fb1,
                        const float* __restrict__ fw2, const float* __restrict__ fb2,
                        float* __restrict__ out) {
  int g = blockIdx.x, t = threadIdx.x;
  __shared__ float row[64];
  float cnt = fmaxf((float)(gstart[g + 1] - gstart[g]), 1.0f);
  row[t] = psum[g * HID + t] / cnt;
  __syncthreads();
  float acc = fb1[t];
  for (int k = 0; k < HID; ++k) acc = fmaf(row[k], fw1[k * HID + t], acc);
  float h = fmaxf(acc, 0.f);
  float v = h * fw2[t];
  for (int o = 32; o > 0; o >>= 1) v += __shfl_down(v, o);
  if (t == 0) out[g] = fmaxf(v + fb2[0], 0.f);
}

// ================= launch =================

extern "C" void kernel_launch(void* const* d_in, const int* in_sizes, int n_in,
                              void* d_out, int out_size, void* d_ws, size_t ws_size,
                              hipStream_t stream) {
  const float* x     = (const float*)d_in[0];
  const int*   ei    = (const int*)d_in[1];
  const int*   batch = (const int*)d_in[2];
  const int* esrc_in = ei;
  const int* edst_in = ei + N_EDGES;

  const float* w1[3], * b1[3], * w2[3], * b2[3], * gg[3], * bt[3];
  for (int l = 0; l < 3; ++l) {
    w1[l] = (const float*)d_in[3 + 6 * l];
    b1[l] = (const float*)d_in[4 + 6 * l];
    w2[l] = (const float*)d_in[5 + 6 * l];
    b2[l] = (const float*)d_in[6 + 6 * l];
    gg[l] = (const float*)d_in[7 + 6 * l];
    bt[l] = (const float*)d_in[8 + 6 * l];
  }
  const float* fw1 = (const float*)d_in[21];
  const float* fb1 = (const float*)d_in[22];
  const float* fw2 = (const float*)d_in[23];
  const float* fb2 = (const float*)d_in[24];

  char* p = (char*)d_ws;
  u16*   xb     = (u16*)p;     p += (size_t)N_NODES * HID * 2;   // 12.8 MB
  u16*   shA    = (u16*)p;     p += (size_t)N_NODES * HID * 2;   // 12.8 MB
  u16*   shB    = (u16*)p;     p += (size_t)N_NODES * HID * 2;   // 12.8 MB (bout overlay)
  int2*  bout   = (int2*)shB;                                    // dead before mlp L2 writes shB
  u16*   aggB   = (u16*)p;     p += (size_t)N_NODES * HID * 2;   // 12.8 MB
  int*   esrc   = (int*)p;     p += (size_t)N_EDGES * 4;         // 6.4 MB
  int*   off    = (int*)p;     p += 400016;                      // N_NODES+1 ints
  float* part   = (float*)p;   p += (size_t)NPARTS * 128 * 4;    // ~800 KB
  float* part2  = (float*)p;   p += (size_t)RED_BLKS * 128 * 4;  // 32 KB
  int*   blockHist = (int*)p;  p += (size_t)SC_NB * NB * 4;      // 613 KB
  int*   blockBase = (int*)p;  p += (size_t)SC_NB * NB * 4;      // 613 KB
  int*   bucketTot = (int*)p;  p += 1024;
  int*   bucketStart = (int*)p; p += 1024;                       // NB+1 ints
  float* sc1    = (float*)p;   p += 512;
  float* sc2    = (float*)p;   p += 512;
  float* sc3    = (float*)p;   p += 512;
  float* psum   = (float*)p;   p += (size_t)NUM_GRAPHS * HID * 4;
  int*   gstart = (int*)p;     p += 1024;
  int*   counters = (int*)p;   p += 64;                          // 3 BN finalize counters
  (void)ws_size; (void)in_sizes; (void)n_in; (void)out_size;

  // ---- CSR build v3 ----
  hipMemsetAsync(counters, 0, 64, stream);
  k_hist<<<SC_NB, 256, 0, stream>>>(edst_in, blockHist);
  k_hscan<<<NB, 1024, 0, stream>>>(blockHist, blockBase, bucketTot);
  k_bscan<<<1, 256, 0, stream>>>(bucketTot, bucketStart);
  k_scatter<<<SC_NB, 256, 0, stream>>>(esrc_in, edst_in, blockBase, bucketStart, bout);
  k_build<<<NB, 512, 0, stream>>>(bout, bucketStart, off, esrc);
  k_bounds<<<1, 192, 0, stream>>>(batch, gstart);
  k_tobf16<<<N_NODES * 16 / 256, 256, 0, stream>>>(x, xb);

  // ---- 3 GIN layers (BN fused into next gather / pooling; stats fused into MLP) ----
  k_gather<false><<<N_NODES * 64 / 256, 256, 0, stream>>>(xb, off, esrc, nullptr, aggB);
  k_mlp<<<MLP_BLKS, 128, 0, stream>>>(aggB, w1[0], b1[0], w2[0], b2[0], shA, part);
  k_bnfused<<<RED_BLKS, 256, 0, stream>>>(part, part2, counters + 0, gg[0], bt[0], sc1);

  k_gather<true><<<N_NODES * 64 / 256, 256, 0, stream>>>(shA, off, esrc, sc1, aggB);
  k_mlp<<<MLP_BLKS, 128, 0, stream>>>(aggB, w1[1], b1[1], w2[1], b2[1], shB, part);
  k_bnfused<<<RED_BLKS, 256, 0, stream>>>(part, part2, counters + 1, gg[1], bt[1], sc2);

  k_gather<true><<<N_NODES * 64 / 256, 256, 0, stream>>>(shB, off, esrc, sc2, aggB);
  k_mlp<<<MLP_BLKS, 128, 0, stream>>>(aggB, w1[2], b1[2], w2[2], b2[2], shA, part);
  k_bnfused<<<RED_BLKS, 256, 0, stream>>>(part, part2, counters + 2, gg[2], bt[2], sc3);

  // ---- pool (BN fused, parallel) + head ----
  hipMemsetAsync(psum, 0, (size_t)NUM_GRAPHS * HID * 4, stream);
  k_pool3<<<POOL_BLKS, 256, 0, stream>>>(shA, batch, sc3, psum);
  k_final<<<NUM_GRAPHS, 64, 0, stream>>>(psum, gstart, fw1, fb1, fw2, fb2, (float*)d_out);
}

// Round 13
// 371.600 us; speedup vs baseline: 1.0331x; 1.0331x over previous
//
#include <hip/hip_runtime.h>

typedef unsigned short u16;
typedef unsigned int   u32;
typedef __attribute__((ext_vector_type(4))) float f32x4;

#define N_NODES    100000
#define N_EDGES    1600000
#define HID        64
#define NUM_GRAPHS 128
#define BN_EPS     1e-5f

#define BSH        9                     // 512 nodes per bucket
#define NB         196                   // ceil(100000/512)
#define SC_T       2048                  // edges per scatter block
#define SC_NB      782                   // ceil(1600000/2048)
#define MAXBE      12288                 // LDS cap for edges/bucket

#define NT_MLP     1563                  // ceil(100000/64) 64-node tiles
#define MLP_BLKS   782                   // 2 waves/block -> 1564 waves
#define NPARTS     1564
#define WS         68                    // padded LDS row stride (f32 / u32 elems)

#define RED_BLKS   64                    // stage-1 BN reduction blocks
#define RED_CHUNK  25                    // ceil(NPARTS / RED_BLKS)

#define POOL_BLKS  391                   // ceil(100000/256)

__device__ __forceinline__ float bf2f(u16 u) { return __uint_as_float(((u32)u) << 16); }
__device__ __forceinline__ u16 f2bf(float f) {           // RNE
  u32 u = __float_as_uint(f);
  u32 r = ((u >> 16) & 1u) + 0x7FFFu;
  return (u16)((u + r) >> 16);
}
__device__ __forceinline__ u32 cvtpk(float lo, float hi) {  // pack 2 f32 -> 2 bf16
  u32 r;
  asm("v_cvt_pk_bf16_f32 %0, %1, %2" : "=v"(r) : "v"(lo), "v"(hi));
  return r;
}

// ================= CSR build v3: LDS counting-sort, streaming writes =================

__global__ void k_hist(const int* __restrict__ dst, int* __restrict__ blockHist) {
  __shared__ int h[NB];
  for (int i = threadIdx.x; i < NB; i += 256) h[i] = 0;
  __syncthreads();
  int base = blockIdx.x * SC_T;
  int cnt = min(SC_T, N_EDGES - base);
  for (int i = threadIdx.x; i < cnt; i += 256) atomicAdd(&h[dst[base + i] >> BSH], 1);
  __syncthreads();
  for (int i = threadIdx.x; i < NB; i += 256) blockHist[blockIdx.x * NB + i] = h[i];
}

__global__ void k_hscan(const int* __restrict__ blockHist, int* __restrict__ blockBase,
                        int* __restrict__ bucketTot) {
  __shared__ int s[1024];
  int b = blockIdx.x, t = threadIdx.x;
  int v = (t < SC_NB) ? blockHist[t * NB + b] : 0;
  s[t] = v;
  __syncthreads();
  for (int d = 1; d < 1024; d <<= 1) {
    int x = (t >= d) ? s[t - d] : 0; __syncthreads();
    s[t] += x; __syncthreads();
  }
  if (t < SC_NB) blockBase[t * NB + b] = s[t] - v;
  if (t == 1023) bucketTot[b] = s[1023];
}

__global__ void k_bscan(const int* __restrict__ bucketTot, int* __restrict__ bucketStart) {
  __shared__ int s[256];
  int t = threadIdx.x;
  int v = (t < NB) ? bucketTot[t] : 0;
  s[t] = v;
  __syncthreads();
  for (int d = 1; d < 256; d <<= 1) {
    int x = (t >= d) ? s[t - d] : 0; __syncthreads();
    s[t] += x; __syncthreads();
  }
  if (t < NB) bucketStart[t] = s[t] - v;
  if (t == NB - 1) bucketStart[NB] = s[t];
}

__global__ __launch_bounds__(256) void k_scatter(
    const int* __restrict__ src, const int* __restrict__ dst,
    const int* __restrict__ blockBase, const int* __restrict__ bucketStart,
    int2* __restrict__ bout) {
  __shared__ int2 stage[SC_T];
  __shared__ int2 sorted[SC_T];
  __shared__ int lhist[NB], lscan[NB], lcur[NB];
  __shared__ int sbuf[256];
  int base = blockIdx.x * SC_T;
  int cnt = min(SC_T, N_EDGES - base);
  for (int i = threadIdx.x; i < NB; i += 256) lhist[i] = 0;
  __syncthreads();
  for (int i = threadIdx.x; i < cnt; i += 256) {
    int d = dst[base + i];
    stage[i] = make_int2(src[base + i], d);
    atomicAdd(&lhist[d >> BSH], 1);
  }
  __syncthreads();
  int t = threadIdx.x;
  int v = (t < NB) ? lhist[t] : 0;
  sbuf[t] = v;
  __syncthreads();
  for (int d = 1; d < 256; d <<= 1) {
    int x = (t >= d) ? sbuf[t - d] : 0; __syncthreads();
    sbuf[t] += x; __syncthreads();
  }
  if (t < NB) { lscan[t] = sbuf[t] - v; lcur[t] = sbuf[t] - v; }
  __syncthreads();
  for (int i = threadIdx.x; i < cnt; i += 256) {
    int2 e = stage[i];
    int pos = atomicAdd(&lcur[e.y >> BSH], 1);
    sorted[pos] = e;
  }
  __syncthreads();
  int bb = blockIdx.x * NB;
  for (int i = threadIdx.x; i < cnt; i += 256) {
    int2 e = sorted[i];
    int bk = e.y >> BSH;
    bout[bucketStart[bk] + blockBase[bb + bk] + (i - lscan[bk])] = e;
  }
}

__global__ __launch_bounds__(512) void k_build(
    const int2* __restrict__ bout, const int* __restrict__ bucketStart,
    int* __restrict__ off, int* __restrict__ esrc) {
  __shared__ int lcnt[512], ls[512], lcur[512];
  __shared__ int lout[MAXBE];
  int b = blockIdx.x;
  int node0 = b << BSH;
  int ncnt = min(512, N_NODES - node0);
  int e0 = bucketStart[b], e1 = bucketStart[b + 1];
  int t = threadIdx.x;
  lcnt[t] = 0;
  __syncthreads();
  for (int i = e0 + t; i < e1; i += 512) atomicAdd(&lcnt[bout[i].y - node0], 1);
  __syncthreads();
  int v = lcnt[t];
  ls[t] = v;
  __syncthreads();
  for (int d = 1; d < 512; d <<= 1) {
    int x = (t >= d) ? ls[t - d] : 0; __syncthreads();
    ls[t] += x; __syncthreads();
  }
  int excl = ls[t] - v;
  if (t < ncnt) off[node0 + t] = e0 + excl;
  if (b == NB - 1 && t == 0) off[N_NODES] = e1;
  lcur[t] = excl;
  __syncthreads();
  for (int i = e0 + t; i < e1; i += 512) {
    int2 e = bout[i];
    int pos = atomicAdd(&lcur[e.y - node0], 1);
    lout[pos] = e.x;
  }
  __syncthreads();
  int n = e1 - e0;
  for (int i = t; i < n; i += 512) esrc[e0 + i] = lout[i];
}

// ================= misc =================

__global__ void k_tobf16(const float* __restrict__ in, u16* __restrict__ out) {
  int i = blockIdx.x * blockDim.x + threadIdx.x;
  float4 v = ((const float4*)in)[i];
  ushort4 o;
  o.x = f2bf(v.x); o.y = f2bf(v.y); o.z = f2bf(v.z); o.w = f2bf(v.w);
  ((ushort4*)out)[i] = o;
}

// ================= per-layer kernels =================

template<bool BN>
__global__ void k_gather(const u16* __restrict__ Xb, const int* __restrict__ off,
                         const int* __restrict__ esrc, const float* __restrict__ sc,
                         u16* __restrict__ aggB) {
  int gid = blockIdx.x * blockDim.x + threadIdx.x;
  int w = gid >> 6;
  int t = gid & 63;
  if (w >= N_NODES) return;
  float scale = 1.f, shift = 0.f;
  if (BN) { scale = sc[t]; shift = sc[64 + t]; }
  int s0 = off[w], s1 = off[w + 1];
  float self = bf2f(Xb[(size_t)w * HID + t]);
  float acc = BN ? fmaxf(fmaf(self, scale, shift), 0.f) : self;
  int i = s0;
  for (; i + 8 <= s1; i += 8) {
    int n0 = esrc[i + 0], n1 = esrc[i + 1], n2 = esrc[i + 2], n3 = esrc[i + 3];
    int n4 = esrc[i + 4], n5 = esrc[i + 5], n6 = esrc[i + 6], n7 = esrc[i + 7];
    float v0 = bf2f(Xb[(size_t)n0 * HID + t]);
    float v1 = bf2f(Xb[(size_t)n1 * HID + t]);
    float v2 = bf2f(Xb[(size_t)n2 * HID + t]);
    float v3 = bf2f(Xb[(size_t)n3 * HID + t]);
    float v4 = bf2f(Xb[(size_t)n4 * HID + t]);
    float v5 = bf2f(Xb[(size_t)n5 * HID + t]);
    float v6 = bf2f(Xb[(size_t)n6 * HID + t]);
    float v7 = bf2f(Xb[(size_t)n7 * HID + t]);
    if (BN) {
      v0 = fmaxf(fmaf(v0, scale, shift), 0.f);
      v1 = fmaxf(fmaf(v1, scale, shift), 0.f);
      v2 = fmaxf(fmaf(v2, scale, shift), 0.f);
      v3 = fmaxf(fmaf(v3, scale, shift), 0.f);
      v4 = fmaxf(fmaf(v4, scale, shift), 0.f);
      v5 = fmaxf(fmaf(v5, scale, shift), 0.f);
      v6 = fmaxf(fmaf(v6, scale, shift), 0.f);
      v7 = fmaxf(fmaf(v7, scale, shift), 0.f);
    }
    acc += ((v0 + v1) + (v2 + v3)) + ((v4 + v5) + (v6 + v7));
  }
  for (; i + 4 <= s1; i += 4) {
    int n0 = esrc[i + 0], n1 = esrc[i + 1], n2 = esrc[i + 2], n3 = esrc[i + 3];
    float v0 = bf2f(Xb[(size_t)n0 * HID + t]);
    float v1 = bf2f(Xb[(size_t)n1 * HID + t]);
    float v2 = bf2f(Xb[(size_t)n2 * HID + t]);
    float v3 = bf2f(Xb[(size_t)n3 * HID + t]);
    if (BN) {
      v0 = fmaxf(fmaf(v0, scale, shift), 0.f);
      v1 = fmaxf(fmaf(v1, scale, shift), 0.f);
      v2 = fmaxf(fmaf(v2, scale, shift), 0.f);
      v3 = fmaxf(fmaf(v3, scale, shift), 0.f);
    }
    acc += (v0 + v1) + (v2 + v3);
  }
  for (; i < s1; ++i) {
    float v = bf2f(Xb[(size_t)esrc[i] * HID + t]);
    if (BN) v = fmaxf(fmaf(v, scale, shift), 0.f);
    acc += v;
  }
  aggB[(size_t)w * HID + t] = f2bf(acc);
}

// Register-tiled vector GEMM MLP v4: wave = 64-node tile, lane = 8x8 D sub-block.
__global__ __launch_bounds__(128) void k_mlp(
    const u16* __restrict__ AGGB,
    const float* __restrict__ w1, const float* __restrict__ b1,
    const float* __restrict__ w2, const float* __restrict__ b2,
    u16* __restrict__ OUTB, float* __restrict__ part) {
  __shared__ float Wl[2][64 * WS];       // W1, W2 fp32, padded rows
  __shared__ u32 Abuf[2][32 * WS];       // per-wave A/H tile: [kp][m] bf16-pairs
  int wv = threadIdx.x >> 6, lane = threadIdx.x & 63;

  for (int i = threadIdx.x; i < 4096; i += 128) {
    int r = i >> 6, c = i & 63;
    Wl[0][r * WS + c] = w1[i];
    Wl[1][r * WS + c] = w2[i];
  }
  __syncthreads();

  int gw = blockIdx.x * 2 + wv;
  int mg = lane >> 3, ng = lane & 7;
  int m0 = mg * 8, n0 = ng * 8;

  if (gw >= NT_MLP) {                    // idle tail wave: zero its stats slot
    if (gw < NPARTS)
      for (int i = lane; i < 128; i += 64) part[gw * 128 + i] = 0.f;
    return;
  }

  u32* A2 = Abuf[wv];
  int nodeBase = gw * 64;
  const u32* srcp = (const u32*)(AGGB + (size_t)nodeBase * 64);
  bool full = (nodeBase + 64 <= N_NODES);
  if (full) {
#pragma unroll
    for (int i = 0; i < 32; ++i) {
      int idx = lane + i * 64;           // idx = m*32 + kp
      A2[(idx & 31) * WS + (idx >> 5)] = srcp[idx];
    }
  } else {
    for (int i = 0; i < 32; ++i) {
      int idx = lane + i * 64;
      int m = idx >> 5;
      A2[(idx & 31) * WS + m] = (nodeBase + m < N_NODES) ? srcp[idx] : 0u;
    }
  }

  float acc[8][8];
#pragma unroll
  for (int c = 0; c < 8; ++c) {
    float bv = b1[n0 + c];
#pragma unroll
    for (int r = 0; r < 8; ++r) acc[r][c] = bv;
  }

  // ---- GEMM1 ----
  {
    const float* W = Wl[0];
#pragma unroll 4
    for (int kp = 0; kp < 32; ++kp) {
      uint4 amA = *(const uint4*)(A2 + kp * WS + m0);
      uint4 amB = *(const uint4*)(A2 + kp * WS + m0 + 4);
      f32x4 w0a = *(const f32x4*)(W + (2 * kp) * WS + n0);
      f32x4 w0b = *(const f32x4*)(W + (2 * kp) * WS + n0 + 4);
      f32x4 w1a = *(const f32x4*)(W + (2 * kp + 1) * WS + n0);
      f32x4 w1b = *(const f32x4*)(W + (2 * kp + 1) * WS + n0 + 4);
      float wlo[8], whi[8];
#pragma unroll
      for (int c = 0; c < 4; ++c) {
        wlo[c] = w0a[c]; wlo[c + 4] = w0b[c];
        whi[c] = w1a[c]; whi[c + 4] = w1b[c];
      }
      u32 av[8] = {amA.x, amA.y, amA.z, amA.w, amB.x, amB.y, amB.z, amB.w};
#pragma unroll
      for (int r = 0; r < 8; ++r) {
        float alo = __uint_as_float(av[r] << 16);
        float ahi = __uint_as_float(av[r] & 0xffff0000u);
#pragma unroll
        for (int c = 0; c < 8; ++c) {
          acc[r][c] = fmaf(alo, wlo[c], acc[r][c]);
          acc[r][c] = fmaf(ahi, whi[c], acc[r][c]);
        }
      }
    }
  }

  // relu -> pack bf16 -> H tile in-place (WAR on A2: drain LDS queue first)
  asm volatile("s_waitcnt lgkmcnt(0)" ::: "memory");
#pragma unroll
  for (int p = 0; p < 4; ++p) {
    u32 pk[8];
#pragma unroll
    for (int r = 0; r < 8; ++r)
      pk[r] = cvtpk(fmaxf(acc[r][2 * p], 0.f), fmaxf(acc[r][2 * p + 1], 0.f));
    int kp = ng * 4 + p;
    *(uint4*)(A2 + kp * WS + m0)     = make_uint4(pk[0], pk[1], pk[2], pk[3]);
    *(uint4*)(A2 + kp * WS + m0 + 4) = make_uint4(pk[4], pk[5], pk[6], pk[7]);
  }
  asm volatile("s_waitcnt lgkmcnt(0)" ::: "memory");

#pragma unroll
  for (int c = 0; c < 8; ++c) {
    float bv = b2[n0 + c];
#pragma unroll
    for (int r = 0; r < 8; ++r) acc[r][c] = bv;
  }

  // ---- GEMM2 ----
  {
    const float* W = Wl[1];
#pragma unroll 4
    for (int kp = 0; kp < 32; ++kp) {
      uint4 amA = *(const uint4*)(A2 + kp * WS + m0);
      uint4 amB = *(const uint4*)(A2 + kp * WS + m0 + 4);
      f32x4 w0a = *(const f32x4*)(W + (2 * kp) * WS + n0);
      f32x4 w0b = *(const f32x4*)(W + (2 * kp) * WS + n0 + 4);
      f32x4 w1a = *(const f32x4*)(W + (2 * kp + 1) * WS + n0);
      f32x4 w1b = *(const f32x4*)(W + (2 * kp + 1) * WS + n0 + 4);
      float wlo[8], whi[8];
#pragma unroll
      for (int c = 0; c < 4; ++c) {
        wlo[c] = w0a[c]; wlo[c + 4] = w0b[c];
        whi[c] = w1a[c]; whi[c + 4] = w1b[c];
      }
      u32 av[8] = {amA.x, amA.y, amA.z, amA.w, amB.x, amB.y, amB.z, amB.w};
#pragma unroll
      for (int r = 0; r < 8; ++r) {
        float alo = __uint_as_float(av[r] << 16);
        float ahi = __uint_as_float(av[r] & 0xffff0000u);
#pragma unroll
        for (int c = 0; c < 8; ++c) {
          acc[r][c] = fmaf(alo, wlo[c], acc[r][c]);
          acc[r][c] = fmaf(ahi, whi[c], acc[r][c]);
        }
      }
    }
  }

  // ---- epilogue: bf16 store + fused BN stats (fp32, valid rows only) ----
  float sstat[8], qstat[8];
#pragma unroll
  for (int c = 0; c < 8; ++c) { sstat[c] = 0.f; qstat[c] = 0.f; }
#pragma unroll
  for (int r = 0; r < 8; ++r) {
    int gm = nodeBase + m0 + r;
    if (gm < N_NODES) {
      uint4 o;
      o.x = cvtpk(acc[r][0], acc[r][1]);
      o.y = cvtpk(acc[r][2], acc[r][3]);
      o.z = cvtpk(acc[r][4], acc[r][5]);
      o.w = cvtpk(acc[r][6], acc[r][7]);
      *(uint4*)(OUTB + (size_t)gm * 64 + n0) = o;
#pragma unroll
      for (int c = 0; c < 8; ++c) {
        float v = acc[r][c];
        sstat[c] += v; qstat[c] += v * v;
      }
    }
  }
#pragma unroll
  for (int o = 8; o < 64; o <<= 1) {
#pragma unroll
    for (int c = 0; c < 8; ++c) {
      sstat[c] += __shfl_xor(sstat[c], o);
      qstat[c] += __shfl_xor(qstat[c], o);
    }
  }
  if (mg == 0) {
#pragma unroll
    for (int c = 0; c < 8; ++c) {
      part[gw * 128 + n0 + c] = sstat[c];
      part[gw * 128 + 64 + n0 + c] = qstat[c];
    }
  }
}

// stage-1 BN reduction: part[NPARTS][128] -> part2[RED_BLKS][128], coalesced, parallel
__global__ void k_bnred(const float* __restrict__ part, float* __restrict__ part2) {
  int col = threadIdx.x & 127, sub = threadIdx.x >> 7;     // 256 threads
  int start = blockIdx.x * RED_CHUNK;
  int end = min(start + RED_CHUNK, NPARTS);
  float acc = 0.f;
  for (int r = start + sub; r < end; r += 2) acc += part[r * 128 + col];
  __shared__ float ls[256];
  ls[threadIdx.x] = acc;
  __syncthreads();
  if (threadIdx.x < 128) part2[blockIdx.x * 128 + threadIdx.x] = ls[threadIdx.x] + ls[128 + threadIdx.x];
}

// stage-2: reduce part2[64][128] (32KB) -> BN scale/shift
__global__ void k_bnparams(const float* __restrict__ part2, float* __restrict__ sc,
                           const float* __restrict__ gamma, const float* __restrict__ beta) {
  __shared__ float red[8][128];
  int t = threadIdx.x;          // 1024 threads
  int col = t & 127, grp = t >> 7;
  float acc = 0.f;
  for (int b = grp; b < RED_BLKS; b += 8) acc += part2[b * 128 + col];
  red[grp][col] = acc;
  __syncthreads();
  if (t < 128) {
    float tot = red[0][t] + red[1][t] + red[2][t] + red[3][t]
              + red[4][t] + red[5][t] + red[6][t] + red[7][t];
    red[0][t] = tot;
  }
  __syncthreads();
  if (t < 64) {
    float mean = red[0][t] * (1.0f / N_NODES);
    float var  = red[0][64 + t] * (1.0f / N_NODES) - mean * mean;
    float scale = gamma[t] * rsqrtf(var + BN_EPS);
    sc[t] = scale;
    sc[64 + t] = beta[t] - mean * scale;
  }
}

// ================= pooling + head (batch sorted -> segments) =================

__global__ void k_bounds(const int* __restrict__ batch, int* __restrict__ gstart) {
  int g = threadIdx.x;
  if (g > NUM_GRAPHS) return;
  int lo = 0, hi = N_NODES;
  while (lo < hi) {
    int mid = (lo + hi) >> 1;
    if (batch[mid] < g) lo = mid + 1; else hi = mid;
  }
  gstart[g] = lo;
}

__global__ void k_pool3(const u16* __restrict__ H, const int* __restrict__ batch,
                        const float* __restrict__ sc, float* __restrict__ psum) {
  int wv = threadIdx.x >> 6, lane = threadIdx.x & 63;
  int n0 = (blockIdx.x * 4 + wv) * 64;
  if (n0 >= N_NODES) return;
  int n1 = min(n0 + 64, N_NODES);
  float scale = sc[lane], shift = sc[64 + lane];
  int curg = batch[n0];
  float acc = 0.f;
  if (curg == batch[n1 - 1]) {
    int n = n0;
    for (; n + 8 <= n1; n += 8) {
      float v0 = fmaxf(fmaf(bf2f(H[(size_t)(n + 0) * HID + lane]), scale, shift), 0.f);
      float v1 = fmaxf(fmaf(bf2f(H[(size_t)(n + 1) * HID + lane]), scale, shift), 0.f);
      float v2 = fmaxf(fmaf(bf2f(H[(size_t)(n + 2) * HID + lane]), scale, shift), 0.f);
      float v3 = fmaxf(fmaf(bf2f(H[(size_t)(n + 3) * HID + lane]), scale, shift), 0.f);
      float v4 = fmaxf(fmaf(bf2f(H[(size_t)(n + 4) * HID + lane]), scale, shift), 0.f);
      float v5 = fmaxf(fmaf(bf2f(H[(size_t)(n + 5) * HID + lane]), scale, shift), 0.f);
      float v6 = fmaxf(fmaf(bf2f(H[(size_t)(n + 6) * HID + lane]), scale, shift), 0.f);
      float v7 = fmaxf(fmaf(bf2f(H[(size_t)(n + 7) * HID + lane]), scale, shift), 0.f);
      acc += ((v0 + v1) + (v2 + v3)) + ((v4 + v5) + (v6 + v7));
    }
    for (; n < n1; ++n)
      acc += fmaxf(fmaf(bf2f(H[(size_t)n * HID + lane]), scale, shift), 0.f);
    atomicAdd(&psum[curg * HID + lane], acc);
  } else {
    for (int n = n0; n < n1; ++n) {
      int g = batch[n];
      if (g != curg) { atomicAdd(&psum[curg * HID + lane], acc); acc = 0.f; curg = g; }
      acc += fmaxf(fmaf(bf2f(H[(size_t)n * HID + lane]), scale, shift), 0.f);
    }
    atomicAdd(&psum[curg * HID + lane], acc);
  }
}

__global__ void k_final(const float* __restrict__ psum, const int* __restrict__ gstart,
                        const float* __restrict__ fw1, const float* __restrict__ fb1,
                        const float* __restrict__ fw2, const float* __restrict__ fb2,
                        float* __restrict__ out) {
  int g = blockIdx.x, t = threadIdx.x;
  __shared__ float row[64];
  float cnt = fmaxf((float)(gstart[g + 1] - gstart[g]), 1.0f);
  row[t] = psum[g * HID + t] / cnt;
  __syncthreads();
  float acc = fb1[t];
  for (int k = 0; k < HID; ++k) acc = fmaf(row[k], fw1[k * HID + t], acc);
  float h = fmaxf(acc, 0.f);
  float v = h * fw2[t];
  for (int o = 32; o > 0; o >>= 1) v += __shfl_down(v, o);
  if (t == 0) out[g] = fmaxf(v + fb2[0], 0.f);
}

// ================= launch =================

extern "C" void kernel_launch(void* const* d_in, const int* in_sizes, int n_in,
                              void* d_out, int out_size, void* d_ws, size_t ws_size,
                              hipStream_t stream) {
  const float* x     = (const float*)d_in[0];
  const int*   ei    = (const int*)d_in[1];
  const int*   batch = (const int*)d_in[2];
  const int* esrc_in = ei;
  const int* edst_in = ei + N_EDGES;

  const float* w1[3], * b1[3], * w2[3], * b2[3], * gg[3], * bt[3];
  for (int l = 0; l < 3; ++l) {
    w1[l] = (const float*)d_in[3 + 6 * l];
    b1[l] = (const float*)d_in[4 + 6 * l];
    w2[l] = (const float*)d_in[5 + 6 * l];
    b2[l] = (const float*)d_in[6 + 6 * l];
    gg[l] = (const float*)d_in[7 + 6 * l];
    bt[l] = (const float*)d_in[8 + 6 * l];
  }
  const float* fw1 = (const float*)d_in[21];
  const float* fb1 = (const float*)d_in[22];
  const float* fw2 = (const float*)d_in[23];
  const float* fb2 = (const float*)d_in[24];

  char* p = (char*)d_ws;
  u16*   xb     = (u16*)p;     p += (size_t)N_NODES * HID * 2;   // 12.8 MB
  u16*   shA    = (u16*)p;     p += (size_t)N_NODES * HID * 2;   // 12.8 MB
  u16*   shB    = (u16*)p;     p += (size_t)N_NODES * HID * 2;   // 12.8 MB (bout overlay)
  int2*  bout   = (int2*)shB;                                    // dead before mlp L2 writes shB
  u16*   aggB   = (u16*)p;     p += (size_t)N_NODES * HID * 2;   // 12.8 MB
  int*   esrc   = (int*)p;     p += (size_t)N_EDGES * 4;         // 6.4 MB
  int*   off    = (int*)p;     p += 400016;                      // N_NODES+1 ints
  float* part   = (float*)p;   p += (size_t)NPARTS * 128 * 4;    // ~800 KB
  float* part2  = (float*)p;   p += (size_t)RED_BLKS * 128 * 4;  // 32 KB
  int*   blockHist = (int*)p;  p += (size_t)SC_NB * NB * 4;      // 613 KB
  int*   blockBase = (int*)p;  p += (size_t)SC_NB * NB * 4;      // 613 KB
  int*   bucketTot = (int*)p;  p += 1024;
  int*   bucketStart = (int*)p; p += 1024;                       // NB+1 ints
  float* sc1    = (float*)p;   p += 512;
  float* sc2    = (float*)p;   p += 512;
  float* sc3    = (float*)p;   p += 512;
  float* psum   = (float*)p;   p += (size_t)NUM_GRAPHS * HID * 4;
  int*   gstart = (int*)p;     p += 1024;
  (void)ws_size; (void)in_sizes; (void)n_in; (void)out_size;

  // ---- CSR build v3 ----
  k_hist<<<SC_NB, 256, 0, stream>>>(edst_in, blockHist);
  k_hscan<<<NB, 1024, 0, stream>>>(blockHist, blockBase, bucketTot);
  k_bscan<<<1, 256, 0, stream>>>(bucketTot, bucketStart);
  k_scatter<<<SC_NB, 256, 0, stream>>>(esrc_in, edst_in, blockBase, bucketStart, bout);
  k_build<<<NB, 512, 0, stream>>>(bout, bucketStart, off, esrc);
  k_bounds<<<1, 192, 0, stream>>>(batch, gstart);
  k_tobf16<<<N_NODES * 16 / 256, 256, 0, stream>>>(x, xb);

  // ---- 3 GIN layers (BN fused into next gather / pooling; stats fused into MLP) ----
  k_gather<false><<<N_NODES * 64 / 256, 256, 0, stream>>>(xb, off, esrc, nullptr, aggB);
  k_mlp<<<MLP_BLKS, 128, 0, stream>>>(aggB, w1[0], b1[0], w2[0], b2[0], shA, part);
  k_bnred<<<RED_BLKS, 256, 0, stream>>>(part, part2);
  k_bnparams<<<1, 1024, 0, stream>>>(part2, sc1, gg[0], bt[0]);

  k_gather<true><<<N_NODES * 64 / 256, 256, 0, stream>>>(shA, off, esrc, sc1, aggB);
  k_mlp<<<MLP_BLKS, 128, 0, stream>>>(aggB, w1[1], b1[1], w2[1], b2[1], shB, part);
  k_bnred<<<RED_BLKS, 256, 0, stream>>>(part, part2);
  k_bnparams<<<1, 1024, 0, stream>>>(part2, sc2, gg[1], bt[1]);

  k_gather<true><<<N_NODES * 64 / 256, 256, 0, stream>>>(shB, off, esrc, sc2, aggB);
  k_mlp<<<MLP_BLKS, 128, 0, stream>>>(aggB, w1[2], b1[2], w2[2], b2[2], shA, part);
  k_bnred<<<RED_BLKS, 256, 0, stream>>>(part, part2);
  k_bnparams<<<1, 1024, 0, stream>>>(part2, sc3, gg[2], bt[2]);

  // ---- pool (BN fused, parallel) + head ----
  hipMemsetAsync(psum, 0, (size_t)NUM_GRAPHS * HID * 4, stream);
  k_pool3<<<POOL_BLKS, 256, 0, stream>>>(shA, batch, sc3, psum);
  k_final<<<NUM_GRAPHS, 64, 0, stream>>>(psum, gstart, fw1, fb1, fw2, fb2, (float*)d_out);
}